// Round 14
// baseline (381.970 us; speedup 1.0000x reference)
//
#include <hip/hip_runtime.h>

typedef unsigned long long u64;
typedef unsigned short ushort_t;

#define NA 50000
#define NE 400000
#define NE_PAD 400128  // padded to multiple of 256; sentinel dst=0xFFFF
#define DF 128
#define HID 64
#define NMOL 256
#define NOUT 32
#define NSTEP 3
#define NPB 782  // node_proj blocks: ceil(NA/64)

typedef __attribute__((ext_vector_type(8))) short short8;
typedef __attribute__((ext_vector_type(8))) unsigned short ushort8;
typedef __attribute__((ext_vector_type(4))) float f32x4;

static __device__ __forceinline__ ushort_t f2bf(float f) {
  union { float f; unsigned u; } v; v.f = f;
  unsigned r = v.u + 0x7fffu + ((v.u >> 16) & 1u);
  return (ushort_t)(r >> 16);
}
static __device__ __forceinline__ unsigned f2bf2(float lo, float hi) {
#if __has_builtin(__builtin_amdgcn_cvt_pk_bf16_f32)
  typedef __attribute__((ext_vector_type(2))) __bf16 bf16x2_t;
  union { bf16x2_t v; unsigned u; } r;
  r.v = __builtin_amdgcn_cvt_pk_bf16_f32(lo, hi);
  return r.u;
#else
  return (unsigned)f2bf(lo) | ((unsigned)f2bf(hi) << 16);
#endif
}
static __device__ __forceinline__ float bflo(unsigned d) {
  union { unsigned u; float f; } v; v.u = d << 16; return v.f;
}
static __device__ __forceinline__ float bfhi(unsigned d) {
  union { unsigned u; float f; } v; v.u = d & 0xffff0000u; return v.f;
}

// -------- fused setup: pack weights (B-frag order) + degree histograms -----
__global__ void setup_a(const float* __restrict__ Win, const float* __restrict__ Wh,
                        const float* __restrict__ Wout,
                        ushort_t* __restrict__ WpB, ushort_t* __restrict__ WhB,
                        ushort_t* __restrict__ WoB,
                        const int* __restrict__ dst, const int* __restrict__ mol_ids,
                        int* __restrict__ counts, int* __restrict__ mcnt) {
  int g = blockIdx.x * 256 + threadIdx.x;
  if (g < 3 * 16384) {
    int tt = g / 16384, r = g % 16384;
    int j = r & 7, lane = (r >> 3) & 63, f = r >> 9;
    int kc = f & 3, nt = f >> 2;
    int k = kc * 32 + (lane >> 4) * 8 + j;
    int n = nt * 16 + (lane & 15);
    float v = (n < 64) ? Win[tt * 16384 + k * 64 + n]
                       : Win[tt * 16384 + (128 + k) * 64 + (n - 64)];
    WpB[g] = f2bf(v);
  }
  int g2 = g - 3 * 16384;
  if (g2 >= 0 && g2 < 3 * 4096) {
    int tt = g2 / 4096, r = g2 % 4096;
    int j = r & 7, lane = (r >> 3) & 63, f = r >> 9;
    int kc = f & 1, nt = f >> 1;
    int k = kc * 32 + (lane >> 4) * 8 + j;
    int n = nt * 16 + (lane & 15);
    WhB[g2] = f2bf(Wh[tt * 4096 + k * 64 + n]);
  }
  int g3 = g2 - 3 * 4096;
  if (g3 >= 0 && g3 < 3 * 8192) {
    int tt = g3 / 8192, r = g3 % 8192;
    int j = r & 7, lane = (r >> 3) & 63, f = r >> 9;
    int kc = f & 1, nt = f >> 1;
    int k = kc * 32 + (lane >> 4) * 8 + j;
    int n = nt * 16 + (lane & 15);
    WoB[g3] = f2bf(Wout[tt * 8192 + k * 128 + n]);
  }
  if (g < NE) atomicAdd(&counts[dst[g]], 1);
  if (g < NA) atomicAdd(&mcnt[mol_ids[g]], 1);
}

// per-1024-block inclusive scan of counts; last block also scans mol histogram
__global__ void scan_phase1(const int* __restrict__ counts, int* __restrict__ tmp,
                            int* __restrict__ blk,
                            const int* __restrict__ mcnt, int* __restrict__ mrow) {
  __shared__ int sh[1024];
  int t = threadIdx.x;
  int i = blockIdx.x * 1024 + t;
  sh[t] = (i < NA) ? counts[i] : 0;
  __syncthreads();
  for (int off = 1; off < 1024; off <<= 1) {
    int x = (t >= off) ? sh[t - off] : 0;
    __syncthreads();
    sh[t] += x;
    __syncthreads();
  }
  if (i < NA) tmp[i] = sh[t];
  if (t == 1023) blk[blockIdx.x] = sh[1023];
  if (blockIdx.x == gridDim.x - 1) {  // fold in the molecule scan
    __syncthreads();
    sh[t] = (t < NMOL) ? mcnt[t] : 0;
    __syncthreads();
    for (int off = 1; off < NMOL; off <<= 1) {
      int x = (t >= off && t < NMOL) ? sh[t - off] : 0;
      __syncthreads();
      if (t < NMOL) sh[t] += x;
      __syncthreads();
    }
    if (t < NMOL) mrow[t + 1] = sh[t];
    if (t == 0) mrow[0] = 0;
  }
}

// row_ptr[i+1] = tmp[i] + prefix(blk, bid); prefix computed by wave-reduce
__global__ void scan_phase3(const int* __restrict__ tmp, const int* __restrict__ blk,
                            int* __restrict__ row_ptr) {
  __shared__ int spre_sh;
  int t = threadIdx.x;
  int bid = blockIdx.x;
  if (t < 64) {
    int v = (t < bid) ? blk[t] : 0;  // bid <= 48 < 64
    for (int off = 32; off; off >>= 1) v += __shfl_down(v, off);
    if (t == 0) spre_sh = v;
  }
  __syncthreads();
  int spre = spre_sh;
  int i = bid * 1024 + t;
  if (i < NA) row_ptr[i + 1] = tmp[i] + spre;
  if (i == 0) row_ptr[0] = 0;
}

// scatter edges sorted by dst, packed (dst<<16)|src; + padding sentinels
__global__ void fill_ab(const int* __restrict__ src, const int* __restrict__ dst,
                        const int* __restrict__ row_ptr, int* __restrict__ cursor,
                        unsigned* __restrict__ ds_pack,
                        const int* __restrict__ mol_ids, const int* __restrict__ mrow,
                        int* __restrict__ mcur, int* __restrict__ mol_sorted) {
  int e = blockIdx.x * 256 + threadIdx.x;
  if (e < NE) {
    int d = dst[e];
    int pos = row_ptr[d] + atomicAdd(&cursor[d], 1);
    ds_pack[pos] = ((unsigned)d << 16) | (unsigned)src[e];
  } else if (e < NE_PAD) {
    ds_pack[e] = 0xFFFF0000u;  // sentinel dst (>= NA), src 0
  }
  if (e < NA) {
    int m = mol_ids[e];
    int pos = mrow[m] + atomicAdd(&mcur[m], 1);
    mol_sorted[pos] = e;
  }
}

// ---- sub-run scan over padded edges: opos[e] = sub-run index --------------
__global__ void escan_p1(const unsigned* __restrict__ ds_pack, int* __restrict__ etmp,
                         int* __restrict__ eblk) {
  __shared__ int sh[1024];
  int t = threadIdx.x;
  int i = blockIdx.x * 1024 + t;
  int f = 0;
  if (i < NE_PAD)
    f = ((i & 3) == 0 || (ds_pack[i] >> 16) != (ds_pack[i - 1] >> 16)) ? 1 : 0;
  sh[t] = f;
  __syncthreads();
  for (int off = 1; off < 1024; off <<= 1) {
    int x = (t >= off) ? sh[t - off] : 0;
    __syncthreads();
    sh[t] += x;
    __syncthreads();
  }
  if (i < NE_PAD) etmp[i] = sh[t];
  if (t == 1023) eblk[blockIdx.x] = sh[1023];
}

// opos[i] = etmp[i] + prefix(eblk, bid) - 1; prefix via block tree-reduce
__global__ void escan_p3(const int* __restrict__ etmp, const int* __restrict__ eblk,
                         int* __restrict__ opos) {
  __shared__ int red[1024];
  int t = threadIdx.x;
  int bid = blockIdx.x;
  red[t] = (t < bid) ? eblk[t] : 0;  // bid <= 390 < 1024
  __syncthreads();
  for (int off = 512; off; off >>= 1) {
    if (t < off) red[t] += red[t + off];
    __syncthreads();
  }
  int spre = red[0];
  int i = bid * 1024 + t;
  if (i < NE_PAD) opos[i] = etmp[i] + spre - 1;
}

// -------- node projection (blocks < NPB) + orow build (blocks >= NPB) ------
__global__ __launch_bounds__(256) void proj_orow(
    const float* __restrict__ s_in, const ushort_t* __restrict__ WpB,
    const float* __restrict__ b_in, ushort_t* __restrict__ PQb,
    const int* __restrict__ row_ptr, const int* __restrict__ opos,
    int* __restrict__ orow) {
  if (blockIdx.x >= NPB) {
    int i = (blockIdx.x - NPB) * 256 + threadIdx.x;
    if (i <= NA) orow[i] = opos[row_ptr[i]];
    return;
  }
  const int t = threadIdx.x;
  const int lane = t & 63, wv = t >> 6, quad = lane >> 4, l15 = lane & 15;
  const int n0 = blockIdx.x * 64 + wv * 16;
  int n = n0 + l15; if (n >= NA) n = NA - 1;
  union { short8 v; unsigned d[4]; } a[4];
#pragma unroll
  for (int c = 0; c < 4; c++) {
    const float* p = s_in + (u64)n * 128 + c * 32 + quad * 8;
    float4 f0 = *(const float4*)(p);
    float4 f1 = *(const float4*)(p + 4);
    a[c].d[0] = f2bf2(f0.x, f0.y);
    a[c].d[1] = f2bf2(f0.z, f0.w);
    a[c].d[2] = f2bf2(f1.x, f1.y);
    a[c].d[3] = f2bf2(f1.z, f1.w);
  }
  float binv[4];
#pragma unroll
  for (int nt = 0; nt < 4; nt++) binv[nt] = b_in[nt * 16 + l15];
  f32x4 accs[8];
#pragma unroll
  for (int nt = 0; nt < 8; nt++) {
    f32x4 acc = {0.f, 0.f, 0.f, 0.f};
#pragma unroll
    for (int c = 0; c < 4; c++) {
      short8 b = *(const short8*)&WpB[((nt * 4 + c) * 64 + lane) * 8];
      acc = __builtin_amdgcn_mfma_f32_16x16x32_bf16(a[c].v, b, acc, 0, 0, 0);
    }
    accs[nt] = acc;
  }
#pragma unroll
  for (int np = 0; np < 4; np++) {
    float b0 = (np < 2) ? binv[2 * np] : 0.f;
    float b1 = (np < 2) ? binv[2 * np + 1] : 0.f;
#pragma unroll
    for (int r = 0; r < 4; r++) {
      int nn = n0 + quad * 4 + r;
      if (nn < NA) {
        unsigned pk2 = f2bf2(accs[2 * np][r] + b0, accs[2 * np + 1][r] + b1);
        PQb[(u64)nn * 128 + (2 * np) * 16 + l15] = (ushort_t)(pk2 & 0xffffu);
        PQb[(u64)nn * 128 + (2 * np + 1) * 16 + l15] = (ushort_t)(pk2 >> 16);
      }
    }
  }
}

// ------ fused edge MLP (MFMA) -> packed-bf16 SUB-RUN partial sums ----------
// 256 edges / block (4 waves x 4 tiles of 16); rolling 2-deep gather prefetch.
// Padding edges (dst sentinel 0xFFFF) write to garbage rows >= R, never read.
__global__ __launch_bounds__(256) void edge_msg(
    const ushort_t* __restrict__ PQb,
    const ushort_t* __restrict__ WhB, const ushort_t* __restrict__ WoB,
    const float* __restrict__ b_h, const float* __restrict__ b_out,
    const unsigned* __restrict__ ds_pack, const int* __restrict__ opos,
    unsigned* __restrict__ m_buf) {
  __shared__ unsigned eps[256];
  __shared__ int ops[256];
  __shared__ ushort_t h2s[4][16 * 72];  // per-wave 16 x 64 bf16 (reused across i)
  const int t = threadIdx.x;
  const int lane = t & 63, wv = t >> 6, quad = lane >> 4, l15 = lane & 15;
  const long long e0 = (long long)blockIdx.x * 256;  // NE_PAD % 256 == 0

  eps[t] = ds_pack[e0 + t];
  ops[t] = opos[e0 + t];
  float bh[4], bo[8];
#pragma unroll
  for (int nt = 0; nt < 4; nt++) bh[nt] = b_h[nt * 16 + l15];
#pragma unroll
  for (int nt = 0; nt < 8; nt++) bo[nt] = b_out[nt * 16 + l15];
  __syncthreads();

  // rolling prefetch: 2 buffers, tiles 0 and 1 up front
  union { ushort8 v; unsigned d[4]; } pv[2][2], qv[2][2];
#pragma unroll
  for (int i = 0; i < 2; i++) {
    unsigned pk = eps[wv * 64 + i * 16 + l15];
    int da = pk >> 16, sa = pk & 0xffffu;
#pragma unroll
    for (int c = 0; c < 2; c++) {
      const int col = c * 32 + quad * 8;
      pv[i][c].v = *(const ushort8*)&PQb[(u64)da * 128 + col];
      qv[i][c].v = *(const ushort8*)&PQb[(u64)sa * 128 + 64 + col];
    }
  }

#pragma unroll
  for (int i = 0; i < 4; i++) {
    const int buf = i & 1;
    const int ebl = wv * 64 + i * 16;  // block-local tile base

    // A-frag of h1 = relu(P'[dst] + Q[src]) — consume prefetched buf
    union { short8 v; unsigned d[4]; } a1[2];
#pragma unroll
    for (int c = 0; c < 2; c++) {
#pragma unroll
      for (int k = 0; k < 4; k++) {
        float lo = fmaxf(bflo(pv[buf][c].d[k]) + bflo(qv[buf][c].d[k]), 0.f);
        float hi = fmaxf(bfhi(pv[buf][c].d[k]) + bfhi(qv[buf][c].d[k]), 0.f);
        a1[c].d[k] = f2bf2(lo, hi);
      }
    }
    // refill buf with tile i+2 (loads issue before this tile's compute chain)
    if (i < 2) {
      unsigned pk = eps[wv * 64 + (i + 2) * 16 + l15];
      int da = pk >> 16, sa = pk & 0xffffu;
#pragma unroll
      for (int c = 0; c < 2; c++) {
        const int col = c * 32 + quad * 8;
        pv[buf][c].v = *(const ushort8*)&PQb[(u64)da * 128 + col];
        qv[buf][c].v = *(const ushort8*)&PQb[(u64)sa * 128 + 64 + col];
      }
    }

    // h2 = relu(h1 @ Wh + b_h)
    f32x4 acc1[4];
#pragma unroll
    for (int nt = 0; nt < 4; nt++) {
      f32x4 acc = {0.f, 0.f, 0.f, 0.f};
#pragma unroll
      for (int c = 0; c < 2; c++) {
        short8 b = *(const short8*)&WhB[((nt * 2 + c) * 64 + lane) * 8];
        acc = __builtin_amdgcn_mfma_f32_16x16x32_bf16(a1[c].v, b, acc, 0, 0, 0);
      }
      acc1[nt] = acc;
    }
    // D-layout -> row-major LDS (wave-private; same-wave RAW/WAR via lgkmcnt)
    ushort_t* hb = h2s[wv];
#pragma unroll
    for (int r = 0; r < 4; r++)
#pragma unroll
      for (int np = 0; np < 2; np++) {
        unsigned pk2 = f2bf2(fmaxf(acc1[2 * np][r] + bh[2 * np], 0.f),
                             fmaxf(acc1[2 * np + 1][r] + bh[2 * np + 1], 0.f));
        hb[(quad * 4 + r) * 72 + (2 * np) * 16 + l15] = (ushort_t)(pk2 & 0xffffu);
        hb[(quad * 4 + r) * 72 + (2 * np + 1) * 16 + l15] = (ushort_t)(pk2 >> 16);
      }

    union { short8 v; ushort_t u[8]; } a2[2];
#pragma unroll
    for (int c = 0; c < 2; c++)
      a2[c].v = *(const short8*)&hb[l15 * 72 + c * 32 + quad * 8];

    // m = relu(h2 @ Wout + b_out)
    f32x4 acc2[8];
#pragma unroll
    for (int nt = 0; nt < 8; nt++) {
      f32x4 acc = {0.f, 0.f, 0.f, 0.f};
#pragma unroll
      for (int c = 0; c < 2; c++) {
        short8 b = *(const short8*)&WoB[((nt * 2 + c) * 64 + lane) * 8];
        acc = __builtin_amdgcn_mfma_f32_16x16x32_bf16(a2[c].v, b, acc, 0, 0, 0);
      }
      acc2[nt] = acc;
    }

    // segmented sub-run flush: fp32 partials, packed-pair stores
    {
      const int base = ebl + quad * 4;
      int prev = (int)(eps[base] >> 16);
      int orow_ = ops[base];
      float run[8];
#pragma unroll
      for (int nt = 0; nt < 8; nt++) run[nt] = 0.f;
#pragma unroll
      for (int r = 0; r < 4; r++) {
        int er = base + r;
        int dcur = (int)(eps[er] >> 16);
        if (dcur != prev) {
          unsigned* rowp = m_buf + (u64)orow_ * 64;
#pragma unroll
          for (int k = 0; k < 4; k++)
            rowp[k * 16 + l15] = f2bf2(run[2 * k], run[2 * k + 1]);
#pragma unroll
          for (int nt = 0; nt < 8; nt++) run[nt] = 0.f;
          prev = dcur; orow_ = ops[er];
        }
#pragma unroll
        for (int nt = 0; nt < 8; nt++)
          run[nt] += fmaxf(acc2[nt][r] + bo[nt], 0.f);
      }
      unsigned* rowp = m_buf + (u64)orow_ * 64;
#pragma unroll
      for (int k = 0; k < 4; k++)
        rowp[k * 16 + l15] = f2bf2(run[2 * k], run[2 * k + 1]);
    }
  }
}

// ---- fused dst aggregation + projection; bounds staged in LDS -------------
__global__ __launch_bounds__(256) void agg_proj(
    const unsigned* __restrict__ m_buf, const int* __restrict__ orow,
    const ushort_t* __restrict__ WpB, const float* __restrict__ b_in,
    ushort_t* __restrict__ PQb) {
  __shared__ ushort_t a_s[64 * 136];  // 64 rows x 128 bf16, pitch 136
  __shared__ int obs_s[65];
  const int t = threadIdx.x;
  const int lane = t & 63, wv = t >> 6, quad = lane >> 4, l15 = lane & 15;
  const int n0 = blockIdx.x * 64;
  if (t < 65) {
    int idx = n0 + t; if (idx > NA) idx = NA;
    obs_s[t] = orow[idx];
  }
  __syncthreads();

  for (int r = 0; r < 16; r++) {
    const int d = n0 + wv * 16 + r;
    float s0 = 0.f, s1 = 0.f;
    if (d < NA) {
      int ob = obs_s[wv * 16 + r], oe = obs_s[wv * 16 + r + 1];
      int n = oe - ob;
      float t0 = 0.f, t1 = 0.f, u0 = 0.f, u1 = 0.f, v0 = 0.f, v1 = 0.f;
      int full = n & ~3;
      int e = ob;
      for (; e < ob + full; e += 4) {
        unsigned w0 = m_buf[(u64)(e + 0) * 64 + lane];
        unsigned w1 = m_buf[(u64)(e + 1) * 64 + lane];
        unsigned w2 = m_buf[(u64)(e + 2) * 64 + lane];
        unsigned w3 = m_buf[(u64)(e + 3) * 64 + lane];
        s0 += bflo(w0); s1 += bfhi(w0);
        t0 += bflo(w1); t1 += bfhi(w1);
        u0 += bflo(w2); u1 += bfhi(w2);
        v0 += bflo(w3); v1 += bfhi(w3);
      }
      int rem = n - full;
      if (rem > 0) {
        int i1 = (rem > 1) ? e + 1 : e;
        int i2 = (rem > 2) ? e + 2 : e;
        unsigned w0 = m_buf[(u64)e * 64 + lane];
        unsigned w1 = m_buf[(u64)i1 * 64 + lane];
        unsigned w2 = m_buf[(u64)i2 * 64 + lane];
        s0 += bflo(w0); s1 += bfhi(w0);
        if (rem > 1) { t0 += bflo(w1); t1 += bfhi(w1); }
        if (rem > 2) { u0 += bflo(w2); u1 += bfhi(w2); }
      }
      s0 = (s0 + t0) + (u0 + v0);
      s1 = (s1 + t1) + (u1 + v1);
    }
    const int row = wv * 16 + r;
    unsigned pk2 = f2bf2(s0, s1);
    a_s[row * 136 + quad * 32 + l15] = (ushort_t)(pk2 & 0xffffu);
    a_s[row * 136 + quad * 32 + 16 + l15] = (ushort_t)(pk2 >> 16);
  }
  // wave-private tile: same-wave LDS RAW ordered by lgkmcnt, no barrier

  float binv[4];
#pragma unroll
  for (int nt = 0; nt < 4; nt++) binv[nt] = b_in[nt * 16 + l15];
  short8 a[4];
#pragma unroll
  for (int c = 0; c < 4; c++)
    a[c] = *(const short8*)&a_s[(wv * 16 + l15) * 136 + c * 32 + quad * 8];
  f32x4 accs[8];
#pragma unroll
  for (int nt = 0; nt < 8; nt++) {
    f32x4 acc = {0.f, 0.f, 0.f, 0.f};
#pragma unroll
    for (int c = 0; c < 4; c++) {
      short8 b = *(const short8*)&WpB[((nt * 4 + c) * 64 + lane) * 8];
      acc = __builtin_amdgcn_mfma_f32_16x16x32_bf16(a[c], b, acc, 0, 0, 0);
    }
    accs[nt] = acc;
  }
#pragma unroll
  for (int np = 0; np < 4; np++) {
    float b0 = (np < 2) ? binv[2 * np] : 0.f;
    float b1 = (np < 2) ? binv[2 * np + 1] : 0.f;
#pragma unroll
    for (int r = 0; r < 4; r++) {
      int nn = n0 + wv * 16 + quad * 4 + r;
      if (nn < NA) {
        unsigned pk2 = f2bf2(accs[2 * np][r] + b0, accs[2 * np + 1][r] + b1);
        PQb[(u64)nn * 128 + (2 * np) * 16 + l15] = (ushort_t)(pk2 & 0xffffu);
        PQb[(u64)nn * 128 + (2 * np + 1) * 16 + l15] = (ushort_t)(pk2 >> 16);
      }
    }
  }
}

// ---- final aggregation: m_buf sub-runs -> per-mol sums; bounds in LDS -----
__global__ __launch_bounds__(256) void agg_mol2(
    const unsigned* __restrict__ m_buf, const int* __restrict__ orow,
    const int* __restrict__ mol_sorted, const int* __restrict__ mol_ids,
    float* __restrict__ mol_repr) {
  __shared__ int mids[64], obs[64], oes[64];
  const int t = threadIdx.x;
  const int lane = t & 63, wv = t >> 6;
  const int base = blockIdx.x * 64;
  if (t < 64) {
    int idx = base + t;
    int r = (idx < NA) ? mol_sorted[idx] : 0;
    mids[t] = (idx < NA) ? mol_ids[r] : -1;
    obs[t] = orow[r];
    oes[t] = orow[r + 1];
  }
  __syncthreads();
  const int c0 = (lane >> 4) * 32 + (lane & 15);  // unpacked cols c0, c0+16
  float r0 = 0.f, r1 = 0.f;
  int prev = mids[wv * 16];
  for (int i = 0; i < 16; i++) {
    int li = wv * 16 + i;
    int m = mids[li];
    if (m != prev) {
      if (prev >= 0) {
        atomicAdd(&mol_repr[(u64)prev * 128 + c0], r0);
        atomicAdd(&mol_repr[(u64)prev * 128 + c0 + 16], r1);
      }
      r0 = 0.f; r1 = 0.f; prev = m;
    }
    if (m >= 0) {
      int ob = obs[li], oe = oes[li];
      int n = oe - ob;
      float t0 = 0.f, t1 = 0.f, u0 = 0.f, u1 = 0.f, v0 = 0.f, v1 = 0.f;
      int full = n & ~3;
      int e = ob;
      for (; e < ob + full; e += 4) {
        unsigned w0 = m_buf[(u64)(e + 0) * 64 + lane];
        unsigned w1 = m_buf[(u64)(e + 1) * 64 + lane];
        unsigned w2 = m_buf[(u64)(e + 2) * 64 + lane];
        unsigned w3 = m_buf[(u64)(e + 3) * 64 + lane];
        r0 += bflo(w0); r1 += bfhi(w0);
        t0 += bflo(w1); t1 += bfhi(w1);
        u0 += bflo(w2); u1 += bfhi(w2);
        v0 += bflo(w3); v1 += bfhi(w3);
      }
      int rem = n - full;
      if (rem > 0) {
        int i1 = (rem > 1) ? e + 1 : e;
        int i2 = (rem > 2) ? e + 2 : e;
        unsigned w0 = m_buf[(u64)e * 64 + lane];
        unsigned w1 = m_buf[(u64)i1 * 64 + lane];
        unsigned w2 = m_buf[(u64)i2 * 64 + lane];
        r0 += bflo(w0); r1 += bfhi(w0);
        if (rem > 1) { t0 += bflo(w1); t1 += bfhi(w1); }
        if (rem > 2) { u0 += bflo(w2); u1 += bfhi(w2); }
      }
      r0 += (t0 + u0) + v0;
      r1 += (t1 + u1) + v1;
    }
  }
  if (prev >= 0) {
    atomicAdd(&mol_repr[(u64)prev * 128 + c0], r0);
    atomicAdd(&mol_repr[(u64)prev * 128 + c0 + 16], r1);
  }
}

// ---------------- final tiny MLP per molecule ----------------
__global__ void final_mlp(const float* __restrict__ mol_repr,
                          const float* __restrict__ fc1_w, const float* __restrict__ fc1_b,
                          const float* __restrict__ fc2_w, const float* __restrict__ fc2_b,
                          const float* __restrict__ out_w, const float* __restrict__ out_b,
                          float* __restrict__ out) {
  int m = blockIdx.x, j = threadIdx.x;
  __shared__ float h1sh[64], h2sh[64];
  const float* mr = mol_repr + (u64)m * DF;
  float acc = fc1_b[j];
  for (int d = 0; d < DF; d++) acc = fmaf(mr[d], fc1_w[d * 64 + j], acc);
  h1sh[j] = fmaxf(acc, 0.f);
  __syncthreads();
  acc = fc2_b[j];
  for (int k = 0; k < 64; k++) acc = fmaf(h1sh[k], fc2_w[k * 64 + j], acc);
  h2sh[j] = fmaxf(acc, 0.f);
  __syncthreads();
  if (j < NOUT) {
    acc = out_b[j];
    for (int k = 0; k < 64; k++) acc = fmaf(h2sh[k], out_w[k * NOUT + j], acc);
    out[(u64)m * NOUT + j] = acc;
  }
}

extern "C" void kernel_launch(void* const* d_in, const int* in_sizes, int n_in,
                              void* d_out, int out_size, void* d_ws, size_t ws_size,
                              hipStream_t stream) {
  const float* states = (const float*)d_in[0];
  const float* Win    = (const float*)d_in[1];
  const float* b_in   = (const float*)d_in[2];
  const float* Wh     = (const float*)d_in[3];
  const float* b_h    = (const float*)d_in[4];
  const float* Wout   = (const float*)d_in[5];
  const float* b_out  = (const float*)d_in[6];
  const float* fc1_w  = (const float*)d_in[7];
  const float* fc1_b  = (const float*)d_in[8];
  const float* fc2_w  = (const float*)d_in[9];
  const float* fc2_b  = (const float*)d_in[10];
  const float* out_w  = (const float*)d_in[11];
  const float* out_b  = (const float*)d_in[12];
  const int* src      = (const int*)d_in[13];
  const int* dst      = (const int*)d_in[14];
  const int* mol_ids  = (const int*)d_in[15];

  char* ws = (char*)d_ws;
  u64 o = 0;
  auto alloc = [&](u64 bytes) {
    void* p = ws + o;
    o += (bytes + 255) & ~255ull;
    return p;
  };
  unsigned* m_buf = (unsigned*)alloc((u64)NE * 64 * 4);   // worst-case R = NE
  ushort_t* PQb  = (ushort_t*)alloc((u64)NA * DF * 2);
  ushort_t* WpB  = (ushort_t*)alloc(3 * 16384 * 2);
  ushort_t* WhB  = (ushort_t*)alloc(3 * 4096 * 2);
  ushort_t* WoB  = (ushort_t*)alloc(3 * 8192 * 2);
  // zero-init block (single memset)
  char* zbase    = ws + o;
  float* molr    = (float*)alloc((u64)NMOL * DF * 4);
  int* counts    = (int*)alloc((u64)NA * 4);
  int* cursor    = (int*)alloc((u64)NA * 4);
  int* mcnt      = (int*)alloc(NMOL * 4);
  int* mcur      = (int*)alloc(NMOL * 4);
  u64 zbytes     = (u64)((ws + o) - zbase);
  int* row_ptr   = (int*)alloc((u64)(NA + 1) * 4);
  int* mrow      = (int*)alloc((NMOL + 1) * 4);
  unsigned* ds_pack = (unsigned*)alloc((u64)NE_PAD * 4);
  int* mol_sorted = (int*)alloc((u64)NA * 4);
  int* scan_tmp  = (int*)alloc((u64)NA * 4);
  int* blk_sums  = (int*)alloc(64 * 4);
  int* opos      = (int*)alloc((u64)(NE_PAD + 1) * 4);
  int* etmp      = (int*)alloc((u64)NE_PAD * 4);
  int* eblk      = (int*)alloc(512 * 4);
  int* orow      = (int*)alloc((u64)(NA + 1) * 4);
  (void)ws_size; (void)in_sizes; (void)n_in; (void)out_size;

  const int NSCAN = (NA + 1023) / 1024;        // 49
  const int NESCAN = (NE_PAD + 1023) / 1024;   // 391
  const int OROWB = (NA + 1 + 255) / 256;      // 196

  hipMemsetAsync(zbase, 0, zbytes, stream);

  setup_a<<<(NE + 255) / 256, 256, 0, stream>>>(Win, Wh, Wout, WpB, WhB, WoB,
                                                dst, mol_ids, counts, mcnt);
  scan_phase1<<<NSCAN, 1024, 0, stream>>>(counts, scan_tmp, blk_sums, mcnt, mrow);
  scan_phase3<<<NSCAN, 1024, 0, stream>>>(scan_tmp, blk_sums, row_ptr);
  fill_ab<<<NE_PAD / 256, 256, 0, stream>>>(src, dst, row_ptr, cursor, ds_pack,
                                            mol_ids, mrow, mcur, mol_sorted);
  escan_p1<<<NESCAN, 1024, 0, stream>>>(ds_pack, etmp, eblk);
  escan_p3<<<NESCAN, 1024, 0, stream>>>(etmp, eblk, opos);

  proj_orow<<<NPB + OROWB, 256, 0, stream>>>(states, WpB, b_in, PQb,
                                             row_ptr, opos, orow);
  for (int t = 0; t < NSTEP; t++) {
    edge_msg<<<NE_PAD / 256, 256, 0, stream>>>(
        PQb, WhB + t * 4096, WoB + t * 8192,
        b_h + t * 64, b_out + t * 128, ds_pack, opos, m_buf);
    if (t < NSTEP - 1) {
      agg_proj<<<(NA + 63) / 64, 256, 0, stream>>>(m_buf, orow,
                                                   WpB + (t + 1) * 16384,
                                                   b_in + (t + 1) * 64, PQb);
    } else {
      agg_mol2<<<(NA + 63) / 64, 256, 0, stream>>>(m_buf, orow, mol_sorted,
                                                   mol_ids, molr);
    }
  }
  final_mlp<<<NMOL, 64, 0, stream>>>(molr, fc1_w, fc1_b, fc2_w, fc2_b, out_w, out_b,
                                     (float*)d_out);
}

// Round 15
// 374.546 us; speedup vs baseline: 1.0198x; 1.0198x over previous
//
#include <hip/hip_runtime.h>

typedef unsigned long long u64;
typedef unsigned short ushort_t;

#define NA 50000
#define NE 400000
#define DF 128
#define HID 64
#define NMOL 256
#define NOUT 32
#define NSTEP 3
#define NPB 782  // node_proj blocks: ceil(NA/64)

typedef __attribute__((ext_vector_type(8))) short short8;
typedef __attribute__((ext_vector_type(8))) unsigned short ushort8;
typedef __attribute__((ext_vector_type(4))) float f32x4;

static __device__ __forceinline__ ushort_t f2bf(float f) {
  union { float f; unsigned u; } v; v.f = f;
  unsigned r = v.u + 0x7fffu + ((v.u >> 16) & 1u);
  return (ushort_t)(r >> 16);
}
static __device__ __forceinline__ float bf2f(unsigned b) {
  union { unsigned u; float f; } v; v.u = b << 16;
  return v.f;
}
static __device__ __forceinline__ float bflo(unsigned d) {
  union { unsigned u; float f; } v; v.u = d << 16; return v.f;
}
static __device__ __forceinline__ float bfhi(unsigned d) {
  union { unsigned u; float f; } v; v.u = d & 0xffff0000u; return v.f;
}

// -------- fused setup: pack weights (B-frag order) + degree histograms -----
__global__ void setup_a(const float* __restrict__ Win, const float* __restrict__ Wh,
                        const float* __restrict__ Wout,
                        ushort_t* __restrict__ WpB, ushort_t* __restrict__ WhB,
                        ushort_t* __restrict__ WoB,
                        const int* __restrict__ dst, const int* __restrict__ mol_ids,
                        int* __restrict__ counts, int* __restrict__ mcnt) {
  int g = blockIdx.x * 256 + threadIdx.x;
  if (g < 3 * 16384) {
    int tt = g / 16384, r = g % 16384;
    int j = r & 7, lane = (r >> 3) & 63, f = r >> 9;
    int kc = f & 3, nt = f >> 2;
    int k = kc * 32 + (lane >> 4) * 8 + j;
    int n = nt * 16 + (lane & 15);
    float v = (n < 64) ? Win[tt * 16384 + k * 64 + n]
                       : Win[tt * 16384 + (128 + k) * 64 + (n - 64)];
    WpB[g] = f2bf(v);
  }
  int g2 = g - 3 * 16384;
  if (g2 >= 0 && g2 < 3 * 4096) {
    int tt = g2 / 4096, r = g2 % 4096;
    int j = r & 7, lane = (r >> 3) & 63, f = r >> 9;
    int kc = f & 1, nt = f >> 1;
    int k = kc * 32 + (lane >> 4) * 8 + j;
    int n = nt * 16 + (lane & 15);
    WhB[g2] = f2bf(Wh[tt * 4096 + k * 64 + n]);
  }
  int g3 = g2 - 3 * 4096;
  if (g3 >= 0 && g3 < 3 * 8192) {
    int tt = g3 / 8192, r = g3 % 8192;
    int j = r & 7, lane = (r >> 3) & 63, f = r >> 9;
    int kc = f & 1, nt = f >> 1;
    int k = kc * 32 + (lane >> 4) * 8 + j;
    int n = nt * 16 + (lane & 15);
    WoB[g3] = f2bf(Wout[tt * 8192 + k * 128 + n]);
  }
  if (g < NE) atomicAdd(&counts[dst[g]], 1);
  if (g < NA) atomicAdd(&mcnt[mol_ids[g]], 1);
}

// per-1024-block inclusive scan of counts; last block also scans mol histogram
__global__ void scan_phase1(const int* __restrict__ counts, int* __restrict__ tmp,
                            int* __restrict__ blk,
                            const int* __restrict__ mcnt, int* __restrict__ mrow) {
  __shared__ int sh[1024];
  int t = threadIdx.x;
  int i = blockIdx.x * 1024 + t;
  sh[t] = (i < NA) ? counts[i] : 0;
  __syncthreads();
  for (int off = 1; off < 1024; off <<= 1) {
    int x = (t >= off) ? sh[t - off] : 0;
    __syncthreads();
    sh[t] += x;
    __syncthreads();
  }
  if (i < NA) tmp[i] = sh[t];
  if (t == 1023) blk[blockIdx.x] = sh[1023];
  if (blockIdx.x == gridDim.x - 1) {  // fold in the molecule scan
    __syncthreads();
    sh[t] = (t < NMOL) ? mcnt[t] : 0;
    __syncthreads();
    for (int off = 1; off < NMOL; off <<= 1) {
      int x = (t >= off && t < NMOL) ? sh[t - off] : 0;
      __syncthreads();
      if (t < NMOL) sh[t] += x;
      __syncthreads();
    }
    if (t < NMOL) mrow[t + 1] = sh[t];
    if (t == 0) mrow[0] = 0;
  }
}

// row_ptr[i+1] = tmp[i] + prefix(blk, bid); prefix computed by wave-reduce
__global__ void scan_phase3(const int* __restrict__ tmp, const int* __restrict__ blk,
                            int* __restrict__ row_ptr) {
  __shared__ int spre_sh;
  int t = threadIdx.x;
  int bid = blockIdx.x;
  if (t < 64) {
    int v = (t < bid) ? blk[t] : 0;  // bid <= 48 < 64
    for (int off = 32; off; off >>= 1) v += __shfl_down(v, off);
    if (t == 0) spre_sh = v;
  }
  __syncthreads();
  int spre = spre_sh;
  int i = bid * 1024 + t;
  if (i < NA) row_ptr[i + 1] = tmp[i] + spre;
  if (i == 0) row_ptr[0] = 0;
}

// scatter edges sorted by dst, packed (dst<<16)|src; + mol_sorted scatter
__global__ void fill_ab(const int* __restrict__ src, const int* __restrict__ dst,
                        const int* __restrict__ row_ptr, int* __restrict__ cursor,
                        unsigned* __restrict__ ds_pack,
                        const int* __restrict__ mol_ids, const int* __restrict__ mrow,
                        int* __restrict__ mcur, int* __restrict__ mol_sorted) {
  int e = blockIdx.x * 256 + threadIdx.x;
  if (e < NE) {
    int d = dst[e];
    int pos = row_ptr[d] + atomicAdd(&cursor[d], 1);
    ds_pack[pos] = ((unsigned)d << 16) | (unsigned)src[e];
  }
  if (e < NA) {
    int m = mol_ids[e];
    int pos = mrow[m] + atomicAdd(&mcur[m], 1);
    mol_sorted[pos] = e;
  }
}

// ---- sub-run scan: opos[e] = index of e's sub-run (4-edge-window x dst) ----
__global__ void escan_p1(const unsigned* __restrict__ ds_pack, int* __restrict__ etmp,
                         int* __restrict__ eblk) {
  __shared__ int sh[1024];
  int t = threadIdx.x;
  int i = blockIdx.x * 1024 + t;
  int f = 0;
  if (i < NE)
    f = ((i & 3) == 0 || (ds_pack[i] >> 16) != (ds_pack[i - 1] >> 16)) ? 1 : 0;
  sh[t] = f;
  __syncthreads();
  for (int off = 1; off < 1024; off <<= 1) {
    int x = (t >= off) ? sh[t - off] : 0;
    __syncthreads();
    sh[t] += x;
    __syncthreads();
  }
  if (i < NE) etmp[i] = sh[t];
  if (t == 1023) eblk[blockIdx.x] = sh[1023];
}

// opos[i] = etmp[i] + prefix(eblk, bid) - 1; prefix via block tree-reduce
__global__ void escan_p3(const int* __restrict__ etmp, const int* __restrict__ eblk,
                         int* __restrict__ opos) {
  __shared__ int red[1024];
  int t = threadIdx.x;
  int bid = blockIdx.x;
  red[t] = (t < bid) ? eblk[t] : 0;  // bid <= 390 < 1024
  __syncthreads();
  for (int off = 512; off; off >>= 1) {
    if (t < off) red[t] += red[t + off];
    __syncthreads();
  }
  int spre = red[0];
  int i = bid * 1024 + t;
  if (i < NE) {
    int v = etmp[i] + spre - 1;
    opos[i] = v;
    if (i == NE - 1) opos[NE] = v + 1;
  }
}

// -------- node projection (blocks < NPB) + orow build (blocks >= NPB) ------
__global__ __launch_bounds__(256) void proj_orow(
    const float* __restrict__ s_in, const ushort_t* __restrict__ WpB,
    const float* __restrict__ b_in, ushort_t* __restrict__ PQb,
    const int* __restrict__ row_ptr, const int* __restrict__ opos,
    int* __restrict__ orow) {
  if (blockIdx.x >= NPB) {
    int i = (blockIdx.x - NPB) * 256 + threadIdx.x;
    if (i <= NA) orow[i] = opos[row_ptr[i]];
    return;
  }
  const int t = threadIdx.x;
  const int lane = t & 63, wv = t >> 6, quad = lane >> 4, l15 = lane & 15;
  const int n0 = blockIdx.x * 64 + wv * 16;
  int n = n0 + l15; if (n >= NA) n = NA - 1;
  union { short8 v; ushort_t u[8]; } a[4];
#pragma unroll
  for (int c = 0; c < 4; c++) {
    const float* p = s_in + (u64)n * 128 + c * 32 + quad * 8;
    float4 f0 = *(const float4*)(p);
    float4 f1 = *(const float4*)(p + 4);
    a[c].u[0] = f2bf(f0.x); a[c].u[1] = f2bf(f0.y);
    a[c].u[2] = f2bf(f0.z); a[c].u[3] = f2bf(f0.w);
    a[c].u[4] = f2bf(f1.x); a[c].u[5] = f2bf(f1.y);
    a[c].u[6] = f2bf(f1.z); a[c].u[7] = f2bf(f1.w);
  }
  float binv[4];
#pragma unroll
  for (int nt = 0; nt < 4; nt++) binv[nt] = b_in[nt * 16 + l15];
#pragma unroll
  for (int nt = 0; nt < 8; nt++) {
    f32x4 acc = {0.f, 0.f, 0.f, 0.f};
#pragma unroll
    for (int c = 0; c < 4; c++) {
      short8 b = *(const short8*)&WpB[((nt * 4 + c) * 64 + lane) * 8];
      acc = __builtin_amdgcn_mfma_f32_16x16x32_bf16(a[c].v, b, acc, 0, 0, 0);
    }
    float bias = (nt < 4) ? binv[nt] : 0.f;
#pragma unroll
    for (int r = 0; r < 4; r++) {
      int nn = n0 + quad * 4 + r;
      if (nn < NA) PQb[(u64)nn * 128 + nt * 16 + l15] = f2bf(acc[r] + bias);
    }
  }
}

// ------ fused edge MLP (MFMA) -> packed-bf16 SUB-RUN partial sums ----------
__global__ __launch_bounds__(256) void edge_msg(
    const ushort_t* __restrict__ PQb,
    const ushort_t* __restrict__ WhB, const ushort_t* __restrict__ WoB,
    const float* __restrict__ b_h, const float* __restrict__ b_out,
    const unsigned* __restrict__ ds_pack, const int* __restrict__ opos,
    unsigned* __restrict__ m_buf) {
  __shared__ unsigned eps[128];
  __shared__ int ops[128];
  __shared__ ushort_t h2s[4][16 * 72];  // per-wave 16 x 64 bf16 (reused across i)
  const int t = threadIdx.x;
  const int lane = t & 63, wv = t >> 6, quad = lane >> 4, l15 = lane & 15;
  const long long e0 = (long long)blockIdx.x * 128;  // NE % 128 == 0

  if (t < 128) {
    eps[t] = ds_pack[e0 + t];
    ops[t] = opos[e0 + t];
  }
  float bh[4], bo[8];
#pragma unroll
  for (int nt = 0; nt < 4; nt++) bh[nt] = b_h[nt * 16 + l15];
#pragma unroll
  for (int nt = 0; nt < 8; nt++) bo[nt] = b_out[nt * 16 + l15];
  __syncthreads();

  // prefetch both tiles' gathers (8 outstanding 16B loads)
  union { ushort8 v; unsigned d[4]; } pv[2][2], qv[2][2];
#pragma unroll
  for (int i = 0; i < 2; i++) {
    unsigned pk = eps[wv * 32 + i * 16 + l15];
    int da = pk >> 16, sa = pk & 0xffffu;
#pragma unroll
    for (int c = 0; c < 2; c++) {
      const int col = c * 32 + quad * 8;
      pv[i][c].v = *(const ushort8*)&PQb[(u64)da * 128 + col];
      qv[i][c].v = *(const ushort8*)&PQb[(u64)sa * 128 + 64 + col];
    }
  }

#pragma unroll
  for (int i = 0; i < 2; i++) {
    const int ebl = wv * 32 + i * 16;  // block-local tile base

    // A-frag of h1 = relu(P'[dst] + Q[src]) from prefetched regs
    union { short8 v; ushort_t u[8]; } a1[2];
#pragma unroll
    for (int c = 0; c < 2; c++) {
#pragma unroll
      for (int k = 0; k < 4; k++) {
        a1[c].u[2 * k] = f2bf(fmaxf(bflo(pv[i][c].d[k]) + bflo(qv[i][c].d[k]), 0.f));
        a1[c].u[2 * k + 1] = f2bf(fmaxf(bfhi(pv[i][c].d[k]) + bfhi(qv[i][c].d[k]), 0.f));
      }
    }

    // h2 = relu(h1 @ Wh + b_h)
    f32x4 acc1[4];
#pragma unroll
    for (int nt = 0; nt < 4; nt++) {
      f32x4 acc = {0.f, 0.f, 0.f, 0.f};
#pragma unroll
      for (int c = 0; c < 2; c++) {
        short8 b = *(const short8*)&WhB[((nt * 2 + c) * 64 + lane) * 8];
        acc = __builtin_amdgcn_mfma_f32_16x16x32_bf16(a1[c].v, b, acc, 0, 0, 0);
      }
      acc1[nt] = acc;
    }
    // D-layout -> row-major LDS (wave-private; same-wave RAW/WAR via lgkmcnt)
    ushort_t* hb = h2s[wv];
#pragma unroll
    for (int nt = 0; nt < 4; nt++)
#pragma unroll
      for (int r = 0; r < 4; r++)
        hb[(quad * 4 + r) * 72 + nt * 16 + l15] =
            f2bf(fmaxf(acc1[nt][r] + bh[nt], 0.f));

    union { short8 v; ushort_t u[8]; } a2[2];
#pragma unroll
    for (int c = 0; c < 2; c++)
      a2[c].v = *(const short8*)&hb[l15 * 72 + c * 32 + quad * 8];

    // m = relu(h2 @ Wout + b_out)
    f32x4 acc2[8];
#pragma unroll
    for (int nt = 0; nt < 8; nt++) {
      f32x4 acc = {0.f, 0.f, 0.f, 0.f};
#pragma unroll
      for (int c = 0; c < 2; c++) {
        short8 b = *(const short8*)&WoB[((nt * 2 + c) * 64 + lane) * 8];
        acc = __builtin_amdgcn_mfma_f32_16x16x32_bf16(a2[c].v, b, acc, 0, 0, 0);
      }
      acc2[nt] = acc;
    }

    // segmented sub-run flush: fp32 partials over the quad's 4 edges
    {
      const int base = ebl + quad * 4;
      int prev = (int)(eps[base] >> 16);
      int orow_ = ops[base];
      float run[8];
#pragma unroll
      for (int nt = 0; nt < 8; nt++) run[nt] = 0.f;
#pragma unroll
      for (int r = 0; r < 4; r++) {
        int er = base + r;
        int dcur = (int)(eps[er] >> 16);
        if (dcur != prev) {
          unsigned* rowp = m_buf + (u64)orow_ * 64;
#pragma unroll
          for (int k = 0; k < 4; k++)
            rowp[k * 16 + l15] =
                (unsigned)f2bf(run[2 * k]) | ((unsigned)f2bf(run[2 * k + 1]) << 16);
#pragma unroll
          for (int nt = 0; nt < 8; nt++) run[nt] = 0.f;
          prev = dcur; orow_ = ops[er];
        }
#pragma unroll
        for (int nt = 0; nt < 8; nt++)
          run[nt] += fmaxf(acc2[nt][r] + bo[nt], 0.f);
      }
      unsigned* rowp = m_buf + (u64)orow_ * 64;
#pragma unroll
      for (int k = 0; k < 4; k++)
        rowp[k * 16 + l15] =
            (unsigned)f2bf(run[2 * k]) | ((unsigned)f2bf(run[2 * k + 1]) << 16);
    }
  }
}

// ---- fused dst aggregation + projection; bounds staged in LDS -------------
__global__ __launch_bounds__(256) void agg_proj(
    const unsigned* __restrict__ m_buf, const int* __restrict__ orow,
    const ushort_t* __restrict__ WpB, const float* __restrict__ b_in,
    ushort_t* __restrict__ PQb) {
  __shared__ ushort_t a_s[64 * 136];  // 64 rows x 128 bf16, pitch 136
  __shared__ int obs_s[65];
  const int t = threadIdx.x;
  const int lane = t & 63, wv = t >> 6, quad = lane >> 4, l15 = lane & 15;
  const int n0 = blockIdx.x * 64;
  if (t < 65) {
    int idx = n0 + t; if (idx > NA) idx = NA;
    obs_s[t] = orow[idx];
  }
  __syncthreads();

  for (int r = 0; r < 16; r++) {
    const int d = n0 + wv * 16 + r;
    float s0 = 0.f, s1 = 0.f;
    if (d < NA) {
      int ob = obs_s[wv * 16 + r], oe = obs_s[wv * 16 + r + 1];
      int n = oe - ob;
      float t0 = 0.f, t1 = 0.f, u0 = 0.f, u1 = 0.f, v0 = 0.f, v1 = 0.f;
      int full = n & ~3;
      int e = ob;
      for (; e < ob + full; e += 4) {
        unsigned w0 = m_buf[(u64)(e + 0) * 64 + lane];
        unsigned w1 = m_buf[(u64)(e + 1) * 64 + lane];
        unsigned w2 = m_buf[(u64)(e + 2) * 64 + lane];
        unsigned w3 = m_buf[(u64)(e + 3) * 64 + lane];
        s0 += bflo(w0); s1 += bfhi(w0);
        t0 += bflo(w1); t1 += bfhi(w1);
        u0 += bflo(w2); u1 += bfhi(w2);
        v0 += bflo(w3); v1 += bfhi(w3);
      }
      int rem = n - full;
      if (rem > 0) {
        int i1 = (rem > 1) ? e + 1 : e;
        int i2 = (rem > 2) ? e + 2 : e;
        unsigned w0 = m_buf[(u64)e * 64 + lane];
        unsigned w1 = m_buf[(u64)i1 * 64 + lane];
        unsigned w2 = m_buf[(u64)i2 * 64 + lane];
        s0 += bflo(w0); s1 += bfhi(w0);
        if (rem > 1) { t0 += bflo(w1); t1 += bfhi(w1); }
        if (rem > 2) { u0 += bflo(w2); u1 += bfhi(w2); }
      }
      s0 = (s0 + t0) + (u0 + v0);
      s1 = (s1 + t1) + (u1 + v1);
    }
    const int row = wv * 16 + r;
    a_s[row * 136 + quad * 32 + l15] = f2bf(s0);
    a_s[row * 136 + quad * 32 + 16 + l15] = f2bf(s1);
  }
  // wave-private tile: same-wave LDS RAW ordered by lgkmcnt, no barrier

  float binv[4];
#pragma unroll
  for (int nt = 0; nt < 4; nt++) binv[nt] = b_in[nt * 16 + l15];
  short8 a[4];
#pragma unroll
  for (int c = 0; c < 4; c++)
    a[c] = *(const short8*)&a_s[(wv * 16 + l15) * 136 + c * 32 + quad * 8];
#pragma unroll
  for (int nt = 0; nt < 8; nt++) {
    f32x4 acc = {0.f, 0.f, 0.f, 0.f};
#pragma unroll
    for (int c = 0; c < 4; c++) {
      short8 b = *(const short8*)&WpB[((nt * 4 + c) * 64 + lane) * 8];
      acc = __builtin_amdgcn_mfma_f32_16x16x32_bf16(a[c], b, acc, 0, 0, 0);
    }
    float bias = (nt < 4) ? binv[nt] : 0.f;
#pragma unroll
    for (int r = 0; r < 4; r++) {
      int nn = n0 + wv * 16 + quad * 4 + r;
      if (nn < NA) PQb[(u64)nn * 128 + nt * 16 + l15] = f2bf(acc[r] + bias);
    }
  }
}

// ---- final aggregation: m_buf sub-runs -> per-mol sums; bounds in LDS -----
__global__ __launch_bounds__(256) void agg_mol2(
    const unsigned* __restrict__ m_buf, const int* __restrict__ orow,
    const int* __restrict__ mol_sorted, const int* __restrict__ mol_ids,
    float* __restrict__ mol_repr) {
  __shared__ int mids[64], obs[64], oes[64];
  const int t = threadIdx.x;
  const int lane = t & 63, wv = t >> 6;
  const int base = blockIdx.x * 64;
  if (t < 64) {
    int idx = base + t;
    int r = (idx < NA) ? mol_sorted[idx] : 0;
    mids[t] = (idx < NA) ? mol_ids[r] : -1;
    obs[t] = orow[r];
    oes[t] = orow[r + 1];
  }
  __syncthreads();
  const int c0 = (lane >> 4) * 32 + (lane & 15);  // unpacked cols c0, c0+16
  float r0 = 0.f, r1 = 0.f;
  int prev = mids[wv * 16];
  for (int i = 0; i < 16; i++) {
    int li = wv * 16 + i;
    int m = mids[li];
    if (m != prev) {
      if (prev >= 0) {
        atomicAdd(&mol_repr[(u64)prev * 128 + c0], r0);
        atomicAdd(&mol_repr[(u64)prev * 128 + c0 + 16], r1);
      }
      r0 = 0.f; r1 = 0.f; prev = m;
    }
    if (m >= 0) {
      int ob = obs[li], oe = oes[li];
      int n = oe - ob;
      float t0 = 0.f, t1 = 0.f, u0 = 0.f, u1 = 0.f, v0 = 0.f, v1 = 0.f;
      int full = n & ~3;
      int e = ob;
      for (; e < ob + full; e += 4) {
        unsigned w0 = m_buf[(u64)(e + 0) * 64 + lane];
        unsigned w1 = m_buf[(u64)(e + 1) * 64 + lane];
        unsigned w2 = m_buf[(u64)(e + 2) * 64 + lane];
        unsigned w3 = m_buf[(u64)(e + 3) * 64 + lane];
        r0 += bflo(w0); r1 += bfhi(w0);
        t0 += bflo(w1); t1 += bfhi(w1);
        u0 += bflo(w2); u1 += bfhi(w2);
        v0 += bflo(w3); v1 += bfhi(w3);
      }
      int rem = n - full;
      if (rem > 0) {
        int i1 = (rem > 1) ? e + 1 : e;
        int i2 = (rem > 2) ? e + 2 : e;
        unsigned w0 = m_buf[(u64)e * 64 + lane];
        unsigned w1 = m_buf[(u64)i1 * 64 + lane];
        unsigned w2 = m_buf[(u64)i2 * 64 + lane];
        r0 += bflo(w0); r1 += bfhi(w0);
        if (rem > 1) { t0 += bflo(w1); t1 += bfhi(w1); }
        if (rem > 2) { u0 += bflo(w2); u1 += bfhi(w2); }
      }
      r0 += (t0 + u0) + v0;
      r1 += (t1 + u1) + v1;
    }
  }
  if (prev >= 0) {
    atomicAdd(&mol_repr[(u64)prev * 128 + c0], r0);
    atomicAdd(&mol_repr[(u64)prev * 128 + c0 + 16], r1);
  }
}

// ---------------- final tiny MLP per molecule ----------------
__global__ void final_mlp(const float* __restrict__ mol_repr,
                          const float* __restrict__ fc1_w, const float* __restrict__ fc1_b,
                          const float* __restrict__ fc2_w, const float* __restrict__ fc2_b,
                          const float* __restrict__ out_w, const float* __restrict__ out_b,
                          float* __restrict__ out) {
  int m = blockIdx.x, j = threadIdx.x;
  __shared__ float h1sh[64], h2sh[64];
  const float* mr = mol_repr + (u64)m * DF;
  float acc = fc1_b[j];
  for (int d = 0; d < DF; d++) acc = fmaf(mr[d], fc1_w[d * 64 + j], acc);
  h1sh[j] = fmaxf(acc, 0.f);
  __syncthreads();
  acc = fc2_b[j];
  for (int k = 0; k < 64; k++) acc = fmaf(h1sh[k], fc2_w[k * 64 + j], acc);
  h2sh[j] = fmaxf(acc, 0.f);
  __syncthreads();
  if (j < NOUT) {
    acc = out_b[j];
    for (int k = 0; k < 64; k++) acc = fmaf(h2sh[k], out_w[k * NOUT + j], acc);
    out[(u64)m * NOUT + j] = acc;
  }
}

extern "C" void kernel_launch(void* const* d_in, const int* in_sizes, int n_in,
                              void* d_out, int out_size, void* d_ws, size_t ws_size,
                              hipStream_t stream) {
  const float* states = (const float*)d_in[0];
  const float* Win    = (const float*)d_in[1];
  const float* b_in   = (const float*)d_in[2];
  const float* Wh     = (const float*)d_in[3];
  const float* b_h    = (const float*)d_in[4];
  const float* Wout   = (const float*)d_in[5];
  const float* b_out  = (const float*)d_in[6];
  const float* fc1_w  = (const float*)d_in[7];
  const float* fc1_b  = (const float*)d_in[8];
  const float* fc2_w  = (const float*)d_in[9];
  const float* fc2_b  = (const float*)d_in[10];
  const float* out_w  = (const float*)d_in[11];
  const float* out_b  = (const float*)d_in[12];
  const int* src      = (const int*)d_in[13];
  const int* dst      = (const int*)d_in[14];
  const int* mol_ids  = (const int*)d_in[15];

  char* ws = (char*)d_ws;
  u64 o = 0;
  auto alloc = [&](u64 bytes) {
    void* p = ws + o;
    o += (bytes + 255) & ~255ull;
    return p;
  };
  unsigned* m_buf = (unsigned*)alloc((u64)NE * 64 * 4);   // worst-case R = NE
  ushort_t* PQb  = (ushort_t*)alloc((u64)NA * DF * 2);
  ushort_t* WpB  = (ushort_t*)alloc(3 * 16384 * 2);
  ushort_t* WhB  = (ushort_t*)alloc(3 * 4096 * 2);
  ushort_t* WoB  = (ushort_t*)alloc(3 * 8192 * 2);
  // zero-init block (single memset)
  char* zbase    = ws + o;
  float* molr    = (float*)alloc((u64)NMOL * DF * 4);
  int* counts    = (int*)alloc((u64)NA * 4);
  int* cursor    = (int*)alloc((u64)NA * 4);
  int* mcnt      = (int*)alloc(NMOL * 4);
  int* mcur      = (int*)alloc(NMOL * 4);
  u64 zbytes     = (u64)((ws + o) - zbase);
  int* row_ptr   = (int*)alloc((u64)(NA + 1) * 4);
  int* mrow      = (int*)alloc((NMOL + 1) * 4);
  unsigned* ds_pack = (unsigned*)alloc((u64)NE * 4);
  int* mol_sorted = (int*)alloc((u64)NA * 4);
  int* scan_tmp  = (int*)alloc((u64)NA * 4);
  int* blk_sums  = (int*)alloc(64 * 4);
  int* opos      = (int*)alloc((u64)(NE + 1) * 4);
  int* etmp      = (int*)alloc((u64)NE * 4);
  int* eblk      = (int*)alloc(512 * 4);
  int* orow      = (int*)alloc((u64)(NA + 1) * 4);
  (void)ws_size; (void)in_sizes; (void)n_in; (void)out_size;

  const int NSCAN = (NA + 1023) / 1024;   // 49
  const int NESCAN = (NE + 1023) / 1024;  // 391
  const int OROWB = (NA + 1 + 255) / 256; // 196

  hipMemsetAsync(zbase, 0, zbytes, stream);

  setup_a<<<(NE + 255) / 256, 256, 0, stream>>>(Win, Wh, Wout, WpB, WhB, WoB,
                                                dst, mol_ids, counts, mcnt);
  scan_phase1<<<NSCAN, 1024, 0, stream>>>(counts, scan_tmp, blk_sums, mcnt, mrow);
  scan_phase3<<<NSCAN, 1024, 0, stream>>>(scan_tmp, blk_sums, row_ptr);
  fill_ab<<<(NE + 255) / 256, 256, 0, stream>>>(src, dst, row_ptr, cursor, ds_pack,
                                                mol_ids, mrow, mcur, mol_sorted);
  escan_p1<<<NESCAN, 1024, 0, stream>>>(ds_pack, etmp, eblk);
  escan_p3<<<NESCAN, 1024, 0, stream>>>(etmp, eblk, opos);

  proj_orow<<<NPB + OROWB, 256, 0, stream>>>(states, WpB, b_in, PQb,
                                             row_ptr, opos, orow);
  for (int t = 0; t < NSTEP; t++) {
    edge_msg<<<(NE + 127) / 128, 256, 0, stream>>>(
        PQb, WhB + t * 4096, WoB + t * 8192,
        b_h + t * 64, b_out + t * 128, ds_pack, opos, m_buf);
    if (t < NSTEP - 1) {
      agg_proj<<<(NA + 63) / 64, 256, 0, stream>>>(m_buf, orow,
                                                   WpB + (t + 1) * 16384,
                                                   b_in + (t + 1) * 64, PQb);
    } else {
      agg_mol2<<<(NA + 63) / 64, 256, 0, stream>>>(m_buf, orow, mol_sorted,
                                                   mol_ids, molr);
    }
  }
  final_mlp<<<NMOL, 64, 0, stream>>>(molr, fc1_w, fc1_b, fc2_w, fc2_b, out_w, out_b,
                                     (float*)d_out);
}